// Round 3
// baseline (674.028 us; speedup 1.0000x reference)
//
#include <hip/hip_runtime.h>

#define FIN 128
#define FHID 32
#define FOUT 64
#define MAXDEG 10

// edge_index arrives as int32 (harness converts integer inputs to int):
// layout [2, E] flat: src = ei[e], dst = ei[E + e].

// ---------- CSR build ----------

__global__ __launch_bounds__(256) void k_count(const int* __restrict__ ei, int E, int N,
                                               int* __restrict__ deg) {
    int e = blockIdx.x * 256 + threadIdx.x;
    if (e >= E) return;
    int d = ei[E + e];
    if ((unsigned)d < (unsigned)N) atomicAdd(deg + d, 1);
}

__global__ __launch_bounds__(256) void k_blocksum(const int* __restrict__ deg, int N,
                                                  int* __restrict__ partial) {
    __shared__ int tmp[256];
    int t = threadIdx.x;
    int i = blockIdx.x * 256 + t;
    tmp[t] = (i < N) ? deg[i] : 0;
    __syncthreads();
    for (int off = 128; off > 0; off >>= 1) {
        if (t < off) tmp[t] += tmp[t + off];
        __syncthreads();
    }
    if (t == 0) partial[blockIdx.x] = tmp[0];
}

// single-block exclusive scan of partial[0..NB) -> offsets   (requires NB <= 1024)
__global__ __launch_bounds__(1024) void k_scanpartial(const int* __restrict__ partial, int NB,
                                                      int* __restrict__ offsets) {
    __shared__ int tmp[1024];
    int t = threadIdx.x;
    int v = (t < NB) ? partial[t] : 0;
    tmp[t] = v;
    __syncthreads();
    for (int off = 1; off < 1024; off <<= 1) {
        int a = (t >= off) ? tmp[t - off] : 0;
        __syncthreads();
        tmp[t] += a;
        __syncthreads();
    }
    if (t < NB) offsets[t] = tmp[t] - v;
}

// cursor[i] = global exclusive scan of deg
__global__ __launch_bounds__(256) void k_scandeg(const int* __restrict__ deg, int N,
                                                 const int* __restrict__ offsets,
                                                 int* __restrict__ cursor) {
    __shared__ int tmp[256];
    int t = threadIdx.x;
    int i = blockIdx.x * 256 + t;
    int v = (i < N) ? deg[i] : 0;
    tmp[t] = v;
    __syncthreads();
    for (int off = 1; off < 256; off <<= 1) {
        int a = (t >= off) ? tmp[t - off] : 0;
        __syncthreads();
        tmp[t] += a;
        __syncthreads();
    }
    if (i < N) cursor[i] = offsets[blockIdx.x] + tmp[t] - v;
}

__global__ __launch_bounds__(256) void k_fill(const int* __restrict__ ei, int E, int N,
                                              int* __restrict__ cursor, int* __restrict__ adj) {
    int e = blockIdx.x * 256 + threadIdx.x;
    if (e >= E) return;
    int s = ei[e];
    int d = ei[E + e];
    if ((unsigned)s >= (unsigned)N || (unsigned)d >= (unsigned)N) return;
    int pos = atomicAdd(cursor + d, 1);   // cursor ends at row end = rowstart + deg
    if ((unsigned)pos < (unsigned)E) adj[pos] = s;
}

// ---------- fused layers: one wave per node ----------

// layer1: gather-sum x rows (128 f, 2 per lane) + 128->32 matvec via shfl broadcast.
// lanes 0..31 accumulate the W1 (neighbor-sum) term, lanes 32..63 the Wr1 (root) term.
__global__ __launch_bounds__(256) void k_layer1(const float* __restrict__ x,
                                                const int* __restrict__ deg,
                                                const int* __restrict__ cursor,
                                                const int* __restrict__ adj,
                                                const float* __restrict__ W1,
                                                const float* __restrict__ b1,
                                                const float* __restrict__ Wr1,
                                                float* __restrict__ out1, int N) {
    int wave = (int)(((long long)blockIdx.x * 256 + threadIdx.x) >> 6);
    if (wave >= N) return;
    int n = wave;
    int lane = threadIdx.x & 63;
    int dg = deg[n];
    int r1 = cursor[n];
    int r0 = r1 - dg;
    float2 hs = make_float2(0.f, 0.f);
    for (int k = r0; k < r1; ++k) {
        int s = adj[k];
        float2 v = *(const float2*)(x + (size_t)s * FIN + lane * 2);
        hs.x += v.x; hs.y += v.y;
    }
    float2 xv = *(const float2*)(x + (size_t)n * FIN + lane * 2);
    int d = dg < MAXDEG ? dg : MAXDEG;
    int o = lane & 31;
    const float* Wp = ((lane < 32) ? W1 : Wr1) + (size_t)d * (FIN * FHID) + o;
    float acc = 0.f;
#pragma unroll
    for (int f = 0; f < FIN; ++f) {
        int sl = f >> 1;
        float hv = __shfl((f & 1) ? hs.y : hs.x, sl);
        float xf = __shfl((f & 1) ? xv.y : xv.x, sl);
        float val = (lane < 32) ? hv : xf;
        acc += val * Wp[f * FHID];
    }
    float other = __shfl_xor(acc, 32);
    if (lane < 32) {
        float r = acc + other + b1[d * FHID + o];
        out1[(size_t)n * FHID + o] = fmaxf(r, 0.f);
    }
}

// layer2: gather-sum y rows (32 f; two neighbors per iter across wave halves)
// + 32->64 matvec; all 64 lanes produce an output channel.
__global__ __launch_bounds__(256) void k_layer2(const float* __restrict__ y,
                                                const int* __restrict__ deg,
                                                const int* __restrict__ cursor,
                                                const int* __restrict__ adj,
                                                const float* __restrict__ W2,
                                                const float* __restrict__ b2,
                                                const float* __restrict__ Wr2,
                                                float* __restrict__ out, int N) {
    int wave = (int)(((long long)blockIdx.x * 256 + threadIdx.x) >> 6);
    if (wave >= N) return;
    int n = wave;
    int lane = threadIdx.x & 63;
    int half = lane >> 5;
    int fh = lane & 31;
    int dg = deg[n];
    int r1 = cursor[n];
    int r0 = r1 - dg;
    float hs = 0.f;
    for (int k = r0 + half; k < r1; k += 2) {
        int s = adj[k];
        hs += y[(size_t)s * FHID + fh];
    }
    hs += __shfl_xor(hs, 32);               // all lanes now hold h[fh]
    float yv = y[(size_t)n * FHID + fh];
    int d = dg < MAXDEG ? dg : MAXDEG;
    const float* Wp  = W2  + (size_t)d * (FHID * FOUT) + lane;
    const float* Wrp = Wr2 + (size_t)d * (FHID * FOUT) + lane;
    float acc = b2[d * FOUT + lane];
#pragma unroll
    for (int f = 0; f < FHID; ++f) {
        float hf = __shfl(hs, f);
        float yf = __shfl(yv, f);
        acc += hf * Wp[f * FOUT] + yf * Wrp[f * FOUT];
    }
    out[(size_t)n * FOUT + lane] = acc;
}

extern "C" void kernel_launch(void* const* d_in, const int* in_sizes, int n_in,
                              void* d_out, int out_size, void* d_ws, size_t ws_size,
                              hipStream_t stream) {
    const float* x   = (const float*)d_in[0];
    const int*   ei  = (const int*)d_in[1];   // int32, [2, E] flat
    const float* W1  = (const float*)d_in[2];
    const float* b1  = (const float*)d_in[3];
    const float* Wr1 = (const float*)d_in[4];
    const float* W2  = (const float*)d_in[5];
    const float* b2  = (const float*)d_in[6];
    const float* Wr2 = (const float*)d_in[7];

    int N = in_sizes[0] / FIN;
    int E = in_sizes[1] / 2;
    int NB = (N + 255) / 256;

    char* ws = (char*)d_ws;
    size_t off = 0;
    auto alloc = [&](size_t bytes) {
        void* p = ws + off;
        off += (bytes + 511) / 512 * 512;
        return p;
    };
    int* deg     = (int*)alloc((size_t)N * sizeof(int));
    int* cursor  = (int*)alloc((size_t)N * sizeof(int));
    int* partial = (int*)alloc((size_t)NB * sizeof(int));
    int* offsets = (int*)alloc((size_t)NB * sizeof(int));
    int* adj     = (int*)alloc((size_t)E * sizeof(int));
    float* out1  = (float*)alloc((size_t)N * FHID * sizeof(float));
    // total ~20.5 MB for N=100K, E=1.6M

    float* out = (float*)d_out;

    hipMemsetAsync(deg, 0, (size_t)N * sizeof(int), stream);

    int eb = (E + 255) / 256;
    k_count<<<eb, 256, 0, stream>>>(ei, E, N, deg);
    k_blocksum<<<NB, 256, 0, stream>>>(deg, N, partial);
    k_scanpartial<<<1, 1024, 0, stream>>>(partial, NB, offsets);
    k_scandeg<<<NB, 256, 0, stream>>>(deg, N, offsets, cursor);
    k_fill<<<eb, 256, 0, stream>>>(ei, E, N, cursor, adj);

    int nb_node = (N + 3) / 4;   // 4 waves (nodes) per 256-thread block
    k_layer1<<<nb_node, 256, 0, stream>>>(x, deg, cursor, adj, W1, b1, Wr1, out1, N);
    k_layer2<<<nb_node, 256, 0, stream>>>(out1, deg, cursor, adj, W2, b2, Wr2, out, N);
}

// Round 4
// 646.706 us; speedup vs baseline: 1.0422x; 1.0422x over previous
//
#include <hip/hip_runtime.h>

#define FIN 128
#define FHID 32
#define FOUT 64
#define MAXDEG 10

// edge_index arrives as int32 (harness converts integer inputs to int):
// layout [2, E] flat: src = ei[e], dst = ei[E + e].

__device__ __forceinline__ float bf2f(unsigned short u) {
    union { unsigned int i; float f; } c; c.i = ((unsigned int)u) << 16; return c.f;
}
__device__ __forceinline__ unsigned short f2bf(float f) {
    union { float f; unsigned int i; } c; c.f = f;
    unsigned int r = c.i + 0x7FFF + ((c.i >> 16) & 1);   // round-nearest-even
    return (unsigned short)(r >> 16);
}

// ---------- CSR build ----------

__global__ __launch_bounds__(256) void k_count(const int* __restrict__ ei, int E, int N,
                                               int* __restrict__ deg) {
    int e = blockIdx.x * 256 + threadIdx.x;
    if (e >= E) return;
    int d = ei[E + e];
    if ((unsigned)d < (unsigned)N) atomicAdd(deg + d, 1);
}

__global__ __launch_bounds__(256) void k_blocksum(const int* __restrict__ deg, int N,
                                                  int* __restrict__ partial) {
    __shared__ int tmp[256];
    int t = threadIdx.x;
    int i = blockIdx.x * 256 + t;
    tmp[t] = (i < N) ? deg[i] : 0;
    __syncthreads();
    for (int off = 128; off > 0; off >>= 1) {
        if (t < off) tmp[t] += tmp[t + off];
        __syncthreads();
    }
    if (t == 0) partial[blockIdx.x] = tmp[0];
}

// single-block exclusive scan of partial[0..NB) -> offsets   (requires NB <= 1024)
__global__ __launch_bounds__(1024) void k_scanpartial(const int* __restrict__ partial, int NB,
                                                      int* __restrict__ offsets) {
    __shared__ int tmp[1024];
    int t = threadIdx.x;
    int v = (t < NB) ? partial[t] : 0;
    tmp[t] = v;
    __syncthreads();
    for (int off = 1; off < 1024; off <<= 1) {
        int a = (t >= off) ? tmp[t - off] : 0;
        __syncthreads();
        tmp[t] += a;
        __syncthreads();
    }
    if (t < NB) offsets[t] = tmp[t] - v;
}

__global__ __launch_bounds__(256) void k_scandeg(const int* __restrict__ deg, int N,
                                                 const int* __restrict__ offsets,
                                                 int* __restrict__ cursor) {
    __shared__ int tmp[256];
    int t = threadIdx.x;
    int i = blockIdx.x * 256 + t;
    int v = (i < N) ? deg[i] : 0;
    tmp[t] = v;
    __syncthreads();
    for (int off = 1; off < 256; off <<= 1) {
        int a = (t >= off) ? tmp[t - off] : 0;
        __syncthreads();
        tmp[t] += a;
        __syncthreads();
    }
    if (i < N) cursor[i] = offsets[blockIdx.x] + tmp[t] - v;
}

__global__ __launch_bounds__(256) void k_fill(const int* __restrict__ ei, int E, int N,
                                              int* __restrict__ cursor, int* __restrict__ adj) {
    int e = blockIdx.x * 256 + threadIdx.x;
    if (e >= E) return;
    int s = ei[e];
    int d = ei[E + e];
    if ((unsigned)s >= (unsigned)N || (unsigned)d >= (unsigned)N) return;
    int pos = atomicAdd(cursor + d, 1);   // cursor ends at row end = rowstart + deg
    if ((unsigned)pos < (unsigned)E) adj[pos] = s;
}

// ---------- pre-transform: z10 = x @ W1[10] (bf16), r1 = x @ Wr1[d_n] + b1[d_n] ----------
// one wave per node: lanes 0-31 -> z10 columns, lanes 32-63 -> r1 columns.
__global__ __launch_bounds__(256) void k_pre1(const float* __restrict__ x,
                                              const int* __restrict__ deg,
                                              const float* __restrict__ W1,
                                              const float* __restrict__ b1,
                                              const float* __restrict__ Wr1,
                                              unsigned short* __restrict__ z10,
                                              float* __restrict__ r1, int N) {
    int wave = (int)(((long long)blockIdx.x * 256 + threadIdx.x) >> 6);
    if (wave >= N) return;
    int n = wave;
    int lane = threadIdx.x & 63;
    float2 xv = *(const float2*)(x + (size_t)n * FIN + lane * 2);
    int d = min(deg[n], MAXDEG);
    int o = lane & 31;
    const float* Wp = (lane < 32) ? (W1 + (size_t)MAXDEG * (FIN * FHID) + o)
                                  : (Wr1 + (size_t)d * (FIN * FHID) + o);
    float acc = 0.f;
#pragma unroll
    for (int f = 0; f < FIN; ++f) {
        float v = __shfl((f & 1) ? xv.y : xv.x, f >> 1);
        acc += v * Wp[f * FHID];
    }
    if (lane < 32) z10[(size_t)n * FHID + o] = f2bf(acc);
    else           r1[(size_t)n * FHID + o] = acc + b1[d * FHID + o];
}

// ---------- layer1: deg>=10 fast path gathers L2-resident bf16 z10 rows ----------
__global__ __launch_bounds__(256) void k_layer1b(const float* __restrict__ x,
                                                 const unsigned short* __restrict__ z10,
                                                 const float* __restrict__ r1,
                                                 const int* __restrict__ deg,
                                                 const int* __restrict__ cursor,
                                                 const int* __restrict__ adj,
                                                 const float* __restrict__ W1,
                                                 unsigned short* __restrict__ out1, int N) {
    int wave = (int)(((long long)blockIdx.x * 256 + threadIdx.x) >> 6);
    if (wave >= N) return;
    int n = wave;
    int lane = threadIdx.x & 63;
    int dg = deg[n];
    int e1 = cursor[n];
    int e0 = e1 - dg;
    if (dg >= MAXDEG) {
        // 4 neighbors in flight: group g (16 lanes) reads neighbor k; lane l holds features (2l,2l+1)
        int g = lane >> 4, l = lane & 15;
        float2 acc = make_float2(0.f, 0.f);
        for (int k = e0 + g; k < e1; k += 4) {
            int s = adj[k];
            ushort2 u = *(const ushort2*)(z10 + (size_t)s * FHID + l * 2);
            acc.x += bf2f(u.x); acc.y += bf2f(u.y);
        }
        acc.x += __shfl_xor(acc.x, 16); acc.y += __shfl_xor(acc.y, 16);
        acc.x += __shfl_xor(acc.x, 32); acc.y += __shfl_xor(acc.y, 32);
        if (lane < 16) {
            float2 r = *(const float2*)(r1 + (size_t)n * FHID + l * 2);
            ushort2 w;
            w.x = f2bf(fmaxf(acc.x + r.x, 0.f));
            w.y = f2bf(fmaxf(acc.y + r.y, 0.f));
            *(ushort2*)(out1 + (size_t)n * FHID + l * 2) = w;
        }
    } else {
        // rare (~2% of edges): gather raw fp32 x rows, matvec with this node's bucket
        float2 hs = make_float2(0.f, 0.f);
        for (int k = e0; k < e1; ++k) {
            int s = adj[k];
            float2 v = *(const float2*)(x + (size_t)s * FIN + lane * 2);
            hs.x += v.x; hs.y += v.y;
        }
        int o = lane & 31;
        const float* Wp = W1 + (size_t)dg * (FIN * FHID) + o;
        float acc = 0.f;
#pragma unroll
        for (int f = 0; f < FIN; ++f) {
            float hv = __shfl((f & 1) ? hs.y : hs.x, f >> 1);
            acc += hv * Wp[f * FHID];
        }
        if (lane < 32) {
            out1[(size_t)n * FHID + o] = f2bf(fmaxf(acc + r1[(size_t)n * FHID + o], 0.f));
        }
    }
}

// ---------- layer2: gather bf16 out1 rows (sum-first), then 32->64 matvec per node ----------
__global__ __launch_bounds__(256) void k_layer2(const unsigned short* __restrict__ y,
                                                const int* __restrict__ deg,
                                                const int* __restrict__ cursor,
                                                const int* __restrict__ adj,
                                                const float* __restrict__ W2,
                                                const float* __restrict__ b2,
                                                const float* __restrict__ Wr2,
                                                float* __restrict__ out, int N) {
    int wave = (int)(((long long)blockIdx.x * 256 + threadIdx.x) >> 6);
    if (wave >= N) return;
    int n = wave;
    int lane = threadIdx.x & 63;
    int dg = deg[n];
    int e1 = cursor[n];
    int e0 = e1 - dg;
    int g = lane >> 4, l = lane & 15;
    float2 acc = make_float2(0.f, 0.f);
    for (int k = e0 + g; k < e1; k += 4) {
        int s = adj[k];
        ushort2 u = *(const ushort2*)(y + (size_t)s * FHID + l * 2);
        acc.x += bf2f(u.x); acc.y += bf2f(u.y);
    }
    acc.x += __shfl_xor(acc.x, 16); acc.y += __shfl_xor(acc.y, 16);
    acc.x += __shfl_xor(acc.x, 32); acc.y += __shfl_xor(acc.y, 32);
    // root features
    ushort2 uy = *(const ushort2*)(y + (size_t)n * FHID + l * 2);
    float2 yv = make_float2(bf2f(uy.x), bf2f(uy.y));
    int d = min(dg, MAXDEG);
    const float* Wp  = W2  + (size_t)d * (FHID * FOUT) + lane;
    const float* Wrp = Wr2 + (size_t)d * (FHID * FOUT) + lane;
    float o_acc = b2[d * FOUT + lane];
#pragma unroll
    for (int f = 0; f < FHID; ++f) {
        float hf = __shfl((f & 1) ? acc.y : acc.x, f >> 1);
        float yf = __shfl((f & 1) ? yv.y  : yv.x,  f >> 1);
        o_acc += hf * Wp[f * FOUT] + yf * Wrp[f * FOUT];
    }
    out[(size_t)n * FOUT + lane] = o_acc;
}

extern "C" void kernel_launch(void* const* d_in, const int* in_sizes, int n_in,
                              void* d_out, int out_size, void* d_ws, size_t ws_size,
                              hipStream_t stream) {
    const float* x   = (const float*)d_in[0];
    const int*   ei  = (const int*)d_in[1];   // int32, [2, E] flat
    const float* W1  = (const float*)d_in[2];
    const float* b1  = (const float*)d_in[3];
    const float* Wr1 = (const float*)d_in[4];
    const float* W2  = (const float*)d_in[5];
    const float* b2  = (const float*)d_in[6];
    const float* Wr2 = (const float*)d_in[7];

    int N = in_sizes[0] / FIN;
    int E = in_sizes[1] / 2;
    int NB = (N + 255) / 256;

    char* ws = (char*)d_ws;
    size_t off = 0;
    auto alloc = [&](size_t bytes) {
        void* p = ws + off;
        off += (bytes + 511) / 512 * 512;
        return p;
    };
    int* deg              = (int*)alloc((size_t)N * sizeof(int));
    int* cursor           = (int*)alloc((size_t)N * sizeof(int));
    int* partial          = (int*)alloc((size_t)NB * sizeof(int));
    int* offsets          = (int*)alloc((size_t)NB * sizeof(int));
    int* adj              = (int*)alloc((size_t)E * sizeof(int));
    unsigned short* z10   = (unsigned short*)alloc((size_t)N * FHID * sizeof(unsigned short));
    float* r1             = (float*)alloc((size_t)N * FHID * sizeof(float));
    unsigned short* out1  = (unsigned short*)alloc((size_t)N * FHID * sizeof(unsigned short));
    // total ~33 MB for N=100K, E=1.6M

    float* out = (float*)d_out;

    hipMemsetAsync(deg, 0, (size_t)N * sizeof(int), stream);

    int eb = (E + 255) / 256;
    k_count<<<eb, 256, 0, stream>>>(ei, E, N, deg);
    k_blocksum<<<NB, 256, 0, stream>>>(deg, N, partial);
    k_scanpartial<<<1, 1024, 0, stream>>>(partial, NB, offsets);
    k_scandeg<<<NB, 256, 0, stream>>>(deg, N, offsets, cursor);
    k_fill<<<eb, 256, 0, stream>>>(ei, E, N, cursor, adj);

    int nb_node = (N + 3) / 4;   // 4 waves (nodes) per 256-thread block
    k_pre1<<<nb_node, 256, 0, stream>>>(x, deg, W1, b1, Wr1, z10, r1, N);
    k_layer1b<<<nb_node, 256, 0, stream>>>(x, z10, r1, deg, cursor, adj, W1, out1, N);
    k_layer2<<<nb_node, 256, 0, stream>>>(out1, deg, cursor, adj, W2, b2, Wr2, out, N);
}